// Round 13
// baseline (68.730 us; speedup 1.0000x reference)
//
#include <hip/hip_runtime.h>
#include <stdint.h>
#include <stddef.h>

typedef __bf16 bf16;
typedef __attribute__((ext_vector_type(8))) __bf16 bf16x8;
typedef __attribute__((ext_vector_type(4))) __bf16 bf16x4;
typedef __attribute__((ext_vector_type(4))) float  f32x4;
typedef __attribute__((ext_vector_type(16))) float f32x16;

// ---------------- geometry ----------------
// B = 262144. node: (B,19,4) f32, edge: (B,36,4) f32.
// compact first-4 nonzero rows -> x[32]; L1 32->256 relu; L2 256->128 relu;
// L3 128->34 (pad 64); log_softmax. Output (B,34) f32.
//
// T=2: each wave processes TWO 32-sample tiles per pass; every weight frag and
// bias chunk is read from LDS once and reused from registers for both tiles.
// This halves the per-sample LDS-pipe load (the measured ~41us/CU wall).
//
// 32x32x16 layouts (verified R12): A lane l = W[k0..k0+8)[n], n=l&31,
// k0(frag t)=t*16+8*(l>>5); B lane l = x[k0..k0+8)[col=l&31]; D col=lane&31,
// row=(reg&3)+8*(reg>>2)+4*(lane>>5).
//
// Weight image in d_ws (R12 layout, verified):
//   W1 @0:   16 frags x 1KB; W2 @16K: 64 frags x 1KB; W3 @80K: 16 frags x 1KB
//   bias D-frag images @96K: L1 8 chunks x 128B, L2 4, L3 2
#define W1OFF  0
#define W2OFF  (16*1024)
#define W3OFF  (80*1024)
#define BIOFF  (96*1024)
#define BI2OFF (BIOFF + 1024)
#define BI3OFF (BIOFF + 1536)
#define IMGSZ  (96*1024 + 1792)
#define NCHUNK (IMGSZ/16)        // 6256
#define PERW   6144              // per-wave: x tile 4KB (64 samples) + stage 2KB
#define LDSSZ  (IMGSZ + 8*PERW)  // 149248 -> 1 block/CU, 8 waves

#define SWZ(s) ((((s)>>1)&3)<<4)

#define MFMA32(a,b,c) __builtin_amdgcn_mfma_f32_32x32x16_bf16((a),(b),(c),0,0,0)

__global__ void prep_kernel(const float* __restrict__ W1, const float* __restrict__ b1,
                            const float* __restrict__ W2, const float* __restrict__ b2,
                            const float* __restrict__ W3, const float* __restrict__ b3,
                            char* __restrict__ img)
{
  int tid = blockIdx.x * 256 + threadIdx.x;
  if (tid < 1024) {                               // W1: 16 frags
    int frag = tid >> 6, l = tid & 63;
    int c = frag >> 1, t = frag & 1, hi = l >> 5;
    int n = c * 32 + (l & 31), k0 = t * 16 + 8 * hi;
    bf16x8 v;
    #pragma unroll
    for (int j = 0; j < 8; ++j) v[j] = (bf16)W1[(size_t)(k0 + j) * 256 + n];
    *(bf16x8*)(img + (size_t)tid * 16) = v;
  } else if (tid < 5120) {                        // W2: 64 frags
    int e = tid - 1024, frag = e >> 6, l = e & 63;
    int nt2 = frag >> 4, c = (frag >> 1) & 7, t = frag & 1, hi = l >> 5;
    int n = nt2 * 32 + (l & 31), k0 = c * 32 + t * 16 + 8 * hi;
    bf16x8 v;
    #pragma unroll
    for (int j = 0; j < 8; ++j) v[j] = (bf16)W2[(size_t)(k0 + j) * 128 + n];
    *(bf16x8*)(img + W2OFF + (size_t)e * 16) = v;
  } else if (tid < 6144) {                        // W3: 16 frags (N pad 64)
    int e = tid - 5120, frag = e >> 6, l = e & 63;
    int nt3 = frag >> 3, c2 = (frag >> 1) & 3, t = frag & 1, hi = l >> 5;
    int n = nt3 * 32 + (l & 31), k0 = c2 * 32 + t * 16 + 8 * hi;
    bf16x8 v;
    #pragma unroll
    for (int j = 0; j < 8; ++j)
      v[j] = (n < 34) ? (bf16)W3[(size_t)(k0 + j) * 34 + n] : (bf16)0.f;
    *(bf16x8*)(img + W3OFF + (size_t)e * 16) = v;
  } else if (tid < 6144 + 448) {                  // bias D-frag images
    int e = tid - 6144;
    int le, chunk;
    char* dst;
    if (e < 256)      { le = e;       dst = img + BIOFF;  }
    else if (e < 384) { le = e - 256; dst = img + BI2OFF; }
    else              { le = e - 384; dst = img + BI3OFF; }
    chunk = le >> 5;
    int idx = le & 31;
    int hi = idx >> 4, reg = idx & 15;
    int f = chunk * 32 + (reg & 3) + 8 * (reg >> 2) + 4 * hi;
    float v;
    if (e < 256)      v = b1[f];
    else if (e < 384) v = b2[f];
    else              v = (f < 34) ? b3[f] : 0.f;
    ((float*)dst)[le] = v;
  }
}

// (512,1): 1 block/CU (LDS forces it anyway) -> 2 waves/SIMD -> 256-VGPR budget
// per the measured model ((512,2)->128 clamp, (512,4)->64 clamp). T=2 needs ~220.
__global__ __launch_bounds__(512, 1) void mlp_kernel(
    const float* __restrict__ node, const float* __restrict__ edge,
    const char* __restrict__ img, float* __restrict__ out)
{
  __shared__ __align__(16) char sm[LDSSZ];
  const int tid  = threadIdx.x;
  const int lane = tid & 63;
  const int w    = tid >> 6;                 // 0..7
  const int blk  = blockIdx.x;

  // stage weight+bias image to LDS (coalesced 16B copies), one barrier total
  for (int c = tid; c < NCHUNK; c += 512)
    *(f32x4*)(sm + (size_t)c * 16) = *(const f32x4*)(img + (size_t)c * 16);
  __syncthreads();

  char* const xw  = sm + IMGSZ + w * PERW;   // x tile: 64 rows x 64B (4KB)
  char* const stg = xw + 4096;               // shared stage (2KB), A then B

  const int col = lane & 31;                 // sample-in-tile / D col
  const int hi  = lane >> 5;
  const int swz = (col >> 1) & 3;            // stage swizzle
  const int cl  = lane & 3;                  // compaction lane within sample
  const int sl  = lane >> 2;                 // compaction sample (0..15)

  const float4* const np = (const float4*)node;   // 19 float4 per sample
  const float4* const ep = (const float4*)edge;   // 36 float4 per sample

  float4 nf[5], ef[9];

  auto issue_loads = [&](int sbase) {
    const int s = sbase + sl;
    #pragma unroll
    for (int i = 0; i < 5; ++i) {
      const int r = cl + 4 * i;
      nf[i] = (r < 19) ? np[(size_t)s * 19 + r] : make_float4(0.f, 0.f, 0.f, 0.f);
    }
    #pragma unroll
    for (int i = 0; i < 9; ++i)
      ef[i] = ep[(size_t)s * 36 + cl + 4 * i];
  };

  auto compact = [&](char* dst) {            // 16 samples -> rows sl of dst
    uint32_t nm = 0; unsigned long long em = 0;
    #pragma unroll
    for (int i = 0; i < 5; ++i) {
      const int r = cl + 4 * i;
      if (r < 19 && (nf[i].x != 0.f || nf[i].y != 0.f || nf[i].z != 0.f || nf[i].w != 0.f))
        nm |= (1u << r);
    }
    #pragma unroll
    for (int i = 0; i < 9; ++i) {
      const int r = cl + 4 * i;
      if (ef[i].x != 0.f || ef[i].y != 0.f || ef[i].z != 0.f || ef[i].w != 0.f)
        em |= (1ull << r);
    }
    nm |= __shfl_xor(nm, 1); nm |= __shfl_xor(nm, 2);
    em |= __shfl_xor(em, 1); em |= __shfl_xor(em, 2);
    bf16x4 zb; zb[0] = (bf16)0.f; zb[1] = (bf16)0.f; zb[2] = (bf16)0.f; zb[3] = (bf16)0.f;
    *(bf16x4*)(dst + sl * 64 + ((8 * cl)      ^ SWZ(sl))) = zb;
    *(bf16x4*)(dst + sl * 64 + ((8 * cl + 32) ^ SWZ(sl))) = zb;
    #pragma unroll
    for (int i = 0; i < 5; ++i) {
      const int r = cl + 4 * i;
      if (r < 19 && ((nm >> r) & 1u)) {
        const int slot = __popc(nm & ((1u << r) - 1u));
        if (slot < 4) {
          bf16x4 pk; pk[0] = (bf16)nf[i].x; pk[1] = (bf16)nf[i].y; pk[2] = (bf16)nf[i].z; pk[3] = (bf16)nf[i].w;
          *(bf16x4*)(dst + sl * 64 + ((8 * slot) ^ SWZ(sl))) = pk;
        }
      }
    }
    #pragma unroll
    for (int i = 0; i < 9; ++i) {
      const int r = cl + 4 * i;
      if ((em >> r) & 1ull) {
        const int slot = __popcll(em & ((1ull << r) - 1ull));
        if (slot < 4) {
          bf16x4 pk; pk[0] = (bf16)ef[i].x; pk[1] = (bf16)ef[i].y; pk[2] = (bf16)ef[i].z; pk[3] = (bf16)ef[i].w;
          *(bf16x4*)(dst + sl * 64 + ((32 + 8 * slot) ^ SWZ(sl))) = pk;
        }
      }
    }
  };

  auto ldbias = [&](const char* p) -> f32x16 {   // 128B chunk -> f32x16 (by reg)
    const f32x4* q4 = (const f32x4*)(p + hi * 64);
    f32x4 q0 = q4[0], q1 = q4[1], q2 = q4[2], q3 = q4[3];
    f32x16 r;
    #pragma unroll
    for (int i = 0; i < 4; ++i) { r[i] = q0[i]; r[4+i] = q1[i]; r[8+i] = q2[i]; r[12+i] = q3[i]; }
    return r;
  };

  // stage pack + B-frag re-read (verified R12 addressing)
  auto pack_stage = [&](const f32x16& d) {
    #pragma unroll
    for (int q = 0; q < 4; ++q) {
      bf16x4 pk;
      #pragma unroll
      for (int i = 0; i < 4; ++i) pk[i] = (bf16)fmaxf(d[4 * q + i], 0.f);
      *(bf16x4*)(stg + col * 64 + (((q ^ swz) << 4) + hi * 8)) = pk;
    }
  };

  #pragma unroll 1
  for (int p = 0; p < 2; ++p) {
    const int S = blk * 1024 + p * 512 + w * 64;

    // ---- build 64-sample x tile (four 16-sample compacts) ----
    issue_loads(S);       compact(xw);
    issue_loads(S + 16);  compact(xw + 1024);
    issue_loads(S + 32);  compact(xw + 2048);
    issue_loads(S + 48);  compact(xw + 3072);

    // x B-frags: tile A = rows 0..31, tile B = rows 32..63
    bf16x8 xfA0 = *(const bf16x8*)(xw        + col * 64 + ((hi * 16)      ^ SWZ(col)));
    bf16x8 xfA1 = *(const bf16x8*)(xw        + col * 64 + ((32 + hi * 16) ^ SWZ(col)));
    bf16x8 xfB0 = *(const bf16x8*)(xw + 2048 + col * 64 + ((hi * 16)      ^ SWZ(col)));
    bf16x8 xfB1 = *(const bf16x8*)(xw + 2048 + col * 64 + ((32 + hi * 16) ^ SWZ(col)));

    // ---- L1 fused into L2, per 32-feature chunk; weights read ONCE per c ----
    f32x16 acc2A[4], acc2B[4];
    #pragma unroll
    for (int nt2 = 0; nt2 < 4; ++nt2) {
      f32x16 bi = ldbias(sm + BI2OFF + nt2 * 128);
      acc2A[nt2] = bi; acc2B[nt2] = bi;
    }

    #pragma unroll 1
    for (int c = 0; c < 8; ++c) {
      __builtin_amdgcn_sched_barrier(0);
      f32x16 dbias = ldbias(sm + BIOFF + c * 128);
      bf16x8 w10 = *(const bf16x8*)(sm + W1OFF + (c * 2 + 0) * 1024 + lane * 16);
      bf16x8 w11 = *(const bf16x8*)(sm + W1OFF + (c * 2 + 1) * 1024 + lane * 16);
      f32x16 dA = dbias, dB = dbias;
      dA = MFMA32(w10, xfA0, dA);
      dA = MFMA32(w11, xfA1, dA);
      dB = MFMA32(w10, xfB0, dB);
      dB = MFMA32(w11, xfB1, dB);

      // tile A through the stage first, then tile B (same-wave LDS in-order)
      pack_stage(dA);
      bf16x8 sfA0 = *(const bf16x8*)(stg + col * 64 + (((0 + hi) ^ swz) << 4));
      bf16x8 sfA1 = *(const bf16x8*)(stg + col * 64 + (((2 + hi) ^ swz) << 4));
      pack_stage(dB);
      bf16x8 sfB0 = *(const bf16x8*)(stg + col * 64 + (((0 + hi) ^ swz) << 4));
      bf16x8 sfB1 = *(const bf16x8*)(stg + col * 64 + (((2 + hi) ^ swz) << 4));

      #pragma unroll
      for (int nt2 = 0; nt2 < 4; ++nt2) {
        bf16x8 a0 = *(const bf16x8*)(sm + W2OFF + ((nt2 * 8 + c) * 2 + 0) * 1024 + lane * 16);
        bf16x8 a1 = *(const bf16x8*)(sm + W2OFF + ((nt2 * 8 + c) * 2 + 1) * 1024 + lane * 16);
        acc2A[nt2] = MFMA32(a0, sfA0, acc2A[nt2]);
        acc2A[nt2] = MFMA32(a1, sfA1, acc2A[nt2]);
        acc2B[nt2] = MFMA32(a0, sfB0, acc2B[nt2]);
        acc2B[nt2] = MFMA32(a1, sfB1, acc2B[nt2]);
      }
    }

    // ---- L2 out -> L3 (128 -> 64 padded); W3 frags read once per c2 ----
    f32x16 acc3A[2], acc3B[2];
    {
      f32x16 b30 = ldbias(sm + BI3OFF + 0);
      f32x16 b31 = ldbias(sm + BI3OFF + 128);
      acc3A[0] = b30; acc3B[0] = b30;
      acc3A[1] = b31; acc3B[1] = b31;
    }

    #pragma unroll   // static acc2 indexing (rule #20)
    for (int c2 = 0; c2 < 4; ++c2) {
      pack_stage(acc2A[c2]);
      bf16x8 sfA0 = *(const bf16x8*)(stg + col * 64 + (((0 + hi) ^ swz) << 4));
      bf16x8 sfA1 = *(const bf16x8*)(stg + col * 64 + (((2 + hi) ^ swz) << 4));
      pack_stage(acc2B[c2]);
      bf16x8 sfB0 = *(const bf16x8*)(stg + col * 64 + (((0 + hi) ^ swz) << 4));
      bf16x8 sfB1 = *(const bf16x8*)(stg + col * 64 + (((2 + hi) ^ swz) << 4));
      #pragma unroll
      for (int nt3 = 0; nt3 < 2; ++nt3) {
        bf16x8 a0 = *(const bf16x8*)(sm + W3OFF + ((nt3 * 4 + c2) * 2 + 0) * 1024 + lane * 16);
        bf16x8 a1 = *(const bf16x8*)(sm + W3OFF + ((nt3 * 4 + c2) * 2 + 1) * 1024 + lane * 16);
        acc3A[nt3] = MFMA32(a0, sfA0, acc3A[nt3]);
        acc3A[nt3] = MFMA32(a1, sfA1, acc3A[nt3]);
        acc3B[nt3] = MFMA32(a0, sfB0, acc3B[nt3]);
        acc3B[nt3] = MFMA32(a1, sfB1, acc3B[nt3]);
      }
    }

    // ---- log_softmax + store, per tile ----
    #pragma unroll
    for (int tb = 0; tb < 2; ++tb) {
      const f32x16* a3 = tb ? acc3B : acc3A;
      float mx = a3[0][0];
      #pragma unroll
      for (int i = 1; i < 16; ++i) mx = fmaxf(mx, a3[0][i]);
      if (hi == 0) { mx = fmaxf(mx, a3[1][0]); mx = fmaxf(mx, a3[1][1]); }
      mx = fmaxf(mx, __shfl_xor(mx, 32));
      float sum = 0.f;
      #pragma unroll
      for (int i = 0; i < 16; ++i) sum += __expf(a3[0][i] - mx);
      if (hi == 0) sum += __expf(a3[1][0] - mx) + __expf(a3[1][1] - mx);
      sum += __shfl_xor(sum, 32);
      const float lse = mx + __logf(sum);

      float* orow = out + (size_t)(S + tb * 32 + col) * 34;
      #pragma unroll
      for (int q = 0; q < 4; ++q) {
        *(float2*)(orow + 8 * q + 4 * hi)     = make_float2(a3[0][4 * q]     - lse, a3[0][4 * q + 1] - lse);
        *(float2*)(orow + 8 * q + 4 * hi + 2) = make_float2(a3[0][4 * q + 2] - lse, a3[0][4 * q + 3] - lse);
      }
      if (hi == 0)
        *(float2*)(orow + 32) = make_float2(a3[1][0] - lse, a3[1][1] - lse);
    }
  }
}

extern "C" void kernel_launch(void* const* d_in, const int* in_sizes, int n_in,
                              void* d_out, int out_size, void* d_ws, size_t ws_size,
                              hipStream_t stream)
{
  const float* node = (const float*)d_in[0];
  const float* edge = (const float*)d_in[1];
  const float* W1   = (const float*)d_in[2];
  const float* b1   = (const float*)d_in[3];
  const float* W2   = (const float*)d_in[4];
  const float* b2   = (const float*)d_in[5];
  const float* W3   = (const float*)d_in[6];
  const float* b3   = (const float*)d_in[7];
  char* img = (char*)d_ws;

  prep_kernel<<<26, 256, 0, stream>>>(W1, b1, W2, b2, W3, b3, img);
  mlp_kernel<<<256, 512, 0, stream>>>(node, edge, img, (float*)d_out);
}